// Round 10
// baseline (96.201 us; speedup 1.0000x reference)
//
#include <hip/hip_runtime.h>
#include <math.h>
#include <stdint.h>

#define N_ANCH 49104
#define NCLS 80
#define KDET 100
#define CAP 256              // chunk size (candidates per NMS chunk)
#define TPB 1024             // 16 waves/block
#define NBINS 1024
#define NBLK 144             // total blocks; ALL produce (1/144 slice each)
#define NCONS 80             // blocks 0..79 also consume (1 class each)
#define GRID NBLK            // 144 blocks; 16 waves + ~23KB LDS -> 2 blocks/CU cap >= 144
#define SUBCAP 16            // slots per (class, block) sub-list
#define THETA 0.996579f      // targets ~168 candidates/class; exact fallback if wrong
#define QTOT (N_ANCH * NCLS / 4)   // 982080 float4 quads
#define JMAX 16              // Jacobi round bound (serial fallback if exceeded)
#define FLAG_MAGIC 0x5AC10000u     // | block id
#define PADKEY(t) ((0xFFFFFFFFull << 16) | (uint64_t)(t))

// ===== MEASUREMENT ROUND =====
// Produce phase replicated PRODUCE_REPS times before the flag store (idempotent: lcnt
// re-zeroed per rep; same candidate SET lands per sub-list -- slot order may differ,
// consumer rank-sort is order-invariant; subcnt/flag identical). With R7's identity
// P + misc = 16 us and row = 5P + misc + C_new:  P = (row_us - 28.5) / 4.
#define PRODUCE_REPS 5

// ws layout: list [NCLS*NBLK*SUBCAP u64] | subcnt [NCLS*NBLK int] | flags [NBLK u32]
#define LIST_ELEMS ((size_t)NCLS * NBLK * SUBCAP)
#define SUBCNT_OFF (LIST_ELEMS * 8)
#define FLAGS_OFF (SUBCNT_OFF + (size_t)NCLS * NBLK * 4)
#define WS_NEED (FLAGS_OFF + (size_t)NBLK * 4)

// Cross-XCD message passing WITHOUT cache maintenance (relaxed agent-scope atomics;
// producer's __syncthreads drains vmcnt(0) before the flag store).
__device__ __forceinline__ void st_agent_u64(uint64_t* p, uint64_t v) {
    __hip_atomic_store(p, v, __ATOMIC_RELAXED, __HIP_MEMORY_SCOPE_AGENT);
}
__device__ __forceinline__ void st_agent_u32(int* p, int v) {
    __hip_atomic_store(p, v, __ATOMIC_RELAXED, __HIP_MEMORY_SCOPE_AGENT);
}
__device__ __forceinline__ uint64_t ld_agent_u64(const uint64_t* p) {
    return __hip_atomic_load(p, __ATOMIC_RELAXED, __HIP_MEMORY_SCOPE_AGENT);
}
__device__ __forceinline__ int ld_agent_i32(const int* p) {
    return __hip_atomic_load(p, __ATOMIC_RELAXED, __HIP_MEMORY_SCOPE_AGENT);
}
__device__ __forceinline__ uint32_t ld_agent_flag(const uint32_t* p) {
    return __hip_atomic_load(p, __ATOMIC_RELAXED, __HIP_MEMORY_SCOPE_AGENT);
}

// ---------------- produce helper ----------------
__device__ __forceinline__ void collect_quad(int q, float4 v, int* lcnt,
                                             uint64_t* __restrict__ list, int blk) {
    const int n = q / 20;            // anchor: 4q/80
    const int c0 = 4 * (q % 20);     // first class of quad
    float ss[4] = {v.x, v.y, v.z, v.w};
#pragma unroll
    for (int u = 0; u < 4; u++) {
        float s = ss[u];
        if (s > THETA) {
            int c = c0 + u;
            int p = atomicAdd(&lcnt[c], 1);              // LDS atomic only
            if (p < SUBCAP) {
                uint32_t bits = __float_as_uint(s);      // s>0: bit order == value order
                st_agent_u64(&list[((size_t)c * NBLK + blk) * SUBCAP + p],
                             ((uint64_t)(~bits) << 16) | (uint64_t)n);   // score desc, anchor asc
            }
        }
    }
}

// ---------------- shared state for the per-class core ----------------
// ra[] eliminated: areas recomputed from box coords at each use ((z-x)*(w-y) on identical
// float4 values -> bit-identical IoU everywhere).
struct ChunkShared {
    uint64_t keys[CAP];                // real keys at [0,M)
    float4   rbox[CAP];                // boxes in sorted (rank) order
    float    rs[CAP];
    uint64_t smat[CAP * (CAP / 64)];   // ST: column i = "who suppresses i" (j < i)
    uint64_t lwbuf[CAP / 64];          // alive ballot words
    uint64_t s_kw[CAP / 64];           // kept ballot words (Jacobi / result)
    int      s_cw[4];                  // per-victim-word change flags
    float4   kbox[KDET];
    float    kar[KDET], ksc[KDET];
};

__device__ __forceinline__ float box_area(float4 b) {
    return (b.z - b.x) * (b.w - b.y);
}

// rank-sort (M-bounded, b128-paired) -> scatter -> filter-vs-kept -> ST ballots (16-wave
// split, victim prefetch) -> Jacobi fixpoint -> parallel extract. Exact; fallback retained.
// PRE: S.keys[0..M) populated with real keys (unique), barrier done.
__device__ __forceinline__ int process_chunk(ChunkShared& S, int tid, int M, int kc0,
                                             const float* __restrict__ boxes) {
    if (M <= 0) return kc0;                       // uniform across block
    const int lane = tid & 63, wid = tid >> 6;    // wid 0..15
    if (tid < M) {
        const uint64_t key = S.keys[tid];
        const int n = (int)(key & 0xFFFFull);     // real keys only: n < N_ANCH
        const float4 mybox = *(const float4*)(boxes + (size_t)n * 4);
        int rank = 0;
        const int Me = M & ~1;
#pragma unroll 4
        for (int j = 0; j < Me; j += 2) {
            const ulonglong2 kk = *(const ulonglong2*)&S.keys[j];
            rank += (kk.x < key) ? 1 : 0;
            rank += (kk.y < key) ? 1 : 0;
        }
        if (Me < M) rank += (S.keys[Me] < key) ? 1 : 0;
        S.rbox[rank] = mybox;
        S.rs[rank] = __uint_as_float(~((uint32_t)(key >> 16)));
    }
    __syncthreads();
    // ---- filter vs previously-kept boxes (exact chunk continuation) ----
    bool alive = (tid < M);
    if (alive && kc0 > 0) {
        float4 b = S.rbox[tid];
        float arb = box_area(b);
        for (int k2 = 0; k2 < kc0; k2++) {
            float4 kb = S.kbox[k2];
            float ix1 = fmaxf(kb.x, b.x), iy1 = fmaxf(kb.y, b.y);
            float ix2 = fminf(kb.z, b.z), iy2 = fminf(kb.w, b.w);
            float inter = fmaxf(ix2 - ix1, 0.0f) * fmaxf(iy2 - iy1, 0.0f);
            float iou = inter / (S.kar[k2] + arb - inter + 1e-8f);
            if (iou > 0.5f) { alive = false; break; }
        }
    }
    {
        uint64_t bal = __ballot(alive);
        if (lane == 0 && wid < 4) S.lwbuf[wid] = bal;
    }
    // no barrier: lwbuf only read in the serial fallback (behind Jacobi barriers);
    // ST reads rbox (post-scatter barrier) and writes smat (read after post-ST barrier).
    // ---- ST bitmatrix: 10 (vw,ws) pairs over 16 waves; next-victim prefetch ----
    {
        int p, istart, istep;
        if (wid < 12) { p = wid >> 1; istart = wid & 1; istep = 2; }
        else          { p = wid - 6;  istart = 0;       istep = 1; }
        const int vw = (int)((0x3333222110ull >> (4 * p)) & 0xF);   // victim word
        const int ws = (int)((0x3210210100ull >> (4 * p)) & 0xF);   // suppressor word
        const int i0 = vw << 6;
        if (i0 < M) {
            const int i1 = min(M, i0 + 64);
            const int jj = (ws << 6) + lane;
            float4 bj = S.rbox[jj];                // jj>=M only when ws==vw: masked by jj<i
            float arj = box_area(bj);
            int ifirst = i0 + istart;
            float4 bi = S.rbox[ifirst < i1 ? ifirst : i0];   // victim prefetch (broadcast)
            for (int i = ifirst; i < i1; i += istep) {
                float4 bin = bi;
                if (i + istep < i1) bin = S.rbox[i + istep];
                bool bit = false;
                if (jj < i) {
                    float ari = box_area(bi);
                    float ix1 = fmaxf(bj.x, bi.x), iy1 = fmaxf(bj.y, bi.y);
                    float ix2 = fminf(bj.z, bi.z), iy2 = fminf(bj.w, bi.w);
                    float inter = fmaxf(ix2 - ix1, 0.0f) * fmaxf(iy2 - iy1, 0.0f);
                    float iou = inter / (arj + ari - inter + 1e-8f);   // fp-identical to ref
                    bit = iou > 0.5f;
                }
                uint64_t bb = __ballot(bit);
                if (lane == 0) S.smat[((size_t)i << 2) + ws] = bb;
                bi = bin;
            }
        }
    }
    __syncthreads();
    // ---- my ST column into registers ----
    uint64_t st0 = 0, st1 = 0, st2 = 0, st3 = 0;
    if (tid < M) {
        st0 = S.smat[((size_t)tid << 2) + 0];
        if (wid >= 1) st1 = S.smat[((size_t)tid << 2) + 1];
        if (wid >= 2) st2 = S.smat[((size_t)tid << 2) + 2];
        if (wid >= 3) st3 = S.smat[((size_t)tid << 2) + 3];
    }
    // ---- Jacobi to fixpoint ----
    bool kept = alive;
    bool converged = false;
    for (int it = 0; it < JMAX; it++) {
        uint64_t kb = __ballot(kept);
        if (lane == 0 && wid < 4) S.s_kw[wid] = kb;
        __syncthreads();
        const uint64_t k0 = S.s_kw[0], k1 = S.s_kw[1], k2 = S.s_kw[2], k3 = S.s_kw[3];
        const bool sup = ((k0 & st0) | (k1 & st1) | (k2 & st2) | (k3 & st3)) != 0ull;
        const bool nk = alive && !sup;
        uint64_t cb = __ballot(nk != kept);
        if (lane == 0 && wid < 4) S.s_cw[wid] = (cb != 0ull) ? 1 : 0;
        kept = nk;
        __syncthreads();
        if ((S.s_cw[0] | S.s_cw[1] | S.s_cw[2] | S.s_cw[3]) == 0) { converged = true; break; }
    }
    if (!converged) {                              // exact serial fallback
        if (tid == 0) {
            uint64_t lv[4] = {S.lwbuf[0], S.lwbuf[1], S.lwbuf[2], S.lwbuf[3]};
            uint64_t kw[4] = {0, 0, 0, 0};
            for (int i = 0; i < M; i++) {
                const int w = i >> 6, b = i & 63;
                if (!((lv[w] >> b) & 1ull)) continue;
                const uint64_t* row = &S.smat[(size_t)i << 2];
                uint64_t sup = kw[0] & row[0];
                if (w >= 1) sup |= kw[1] & row[1];
                if (w >= 2) sup |= kw[2] & row[2];
                if (w >= 3) sup |= kw[3] & row[3];
                if (!sup) kw[w] |= 1ull << b;
            }
            S.s_kw[0] = kw[0]; S.s_kw[1] = kw[1]; S.s_kw[2] = kw[2]; S.s_kw[3] = kw[3];
        }
        __syncthreads();
    }
    // ---- parallel extraction in greedy (index) order ----
    const uint64_t k0 = S.s_kw[0], k1 = S.s_kw[1], k2 = S.s_kw[2], k3 = S.s_kw[3];
    const int total = __popcll(k0) + __popcll(k1) + __popcll(k2) + __popcll(k3);
    const uint64_t mykw = (wid == 0) ? k0 : (wid == 1) ? k1 : (wid == 2) ? k2 : k3;
    if (tid < M && ((mykw >> lane) & 1ull)) {
        int rk = __popcll(mykw & ((1ull << lane) - 1ull));
        if (wid > 0) rk += __popcll(k0);
        if (wid > 1) rk += __popcll(k1);
        if (wid > 2) rk += __popcll(k2);
        const int r = kc0 + rk;
        if (r < KDET) {
            float4 rb = S.rbox[tid];
            S.kbox[r] = rb;
            S.kar[r] = box_area(rb);
            S.ksc[r] = S.rs[tid];
        }
    }
    __syncthreads();
    return min(kc0 + total, KDET);
}

// ---------------- exact slow path ----------------
__device__ __forceinline__ int slow_path(ChunkShared& S, int* hist, int* s_cnt, int* s_lo,
                                         int c, int kc, bool fast, int tid,
                                         const float* __restrict__ scores,
                                         const float* __restrict__ boxes) {
    const float hicut = fast ? THETA : 3.0e38f;
    if (!fast) kc = 0;
    for (int b = tid; b < NBINS; b += TPB) hist[b] = 0;
    __syncthreads();
    for (int n = tid; n < N_ANCH; n += TPB) {
        float s = scores[(size_t)n * NCLS + c];
        if (s > 0.05f && s <= hicut) {
            int b = (int)(s * 1024.0f);
            b = b < 0 ? 0 : (b > NBINS - 1 ? NBINS - 1 : b);
            atomicAdd(&hist[b], 1);
        }
    }
    __syncthreads();
    int hi = NBINS;
    while (hi > 0 && kc < KDET) {
        if (tid == 0) {
            int lo = hi, tot = 0;
            while (lo > 0 && tot + hist[lo - 1] <= CAP) { lo--; tot += hist[lo]; }
            if (lo == hi) lo = hi - 1;
            *s_lo = lo; *s_cnt = 0;
        }
        __syncthreads();
        const int lo = *s_lo;
        for (int n = tid; n < N_ANCH; n += TPB) {
            float s = scores[(size_t)n * NCLS + c];
            if (s > 0.05f && s <= hicut) {
                int b = (int)(s * 1024.0f);
                b = b < 0 ? 0 : (b > NBINS - 1 ? NBINS - 1 : b);
                if (b >= lo && b < hi) {
                    int p = atomicAdd(s_cnt, 1);
                    if (p < CAP) {
                        uint32_t bits = __float_as_uint(s);
                        S.keys[p] = ((uint64_t)(~bits) << 16) | (uint64_t)n;
                    }
                }
            }
        }
        __syncthreads();
        const int M2 = min(*s_cnt, CAP);
        kc = process_chunk(S, tid, M2, kc, boxes);
        hi = lo;
    }
    return kc;
}

// ---------------- output epilogue ----------------
__device__ __forceinline__ void write_outputs(ChunkShared& S, int c, int kc, int tid,
                                              float* __restrict__ out) {
    float* o_sc = out;
    float* o_cl = out + NCLS * KDET;
    float* o_bx = out + 2 * NCLS * KDET;
    float* o_va = out + 6 * NCLS * KDET;
    for (int k = tid; k < KDET; k += TPB) {
        bool valid = k < kc;
        o_sc[c * KDET + k] = valid ? S.ksc[k] : 0.0f;
        o_cl[c * KDET + k] = (float)c;
        o_va[c * KDET + k] = valid ? 1.0f : 0.0f;
        float4 bo;
        if (valid) bo = S.kbox[k];
        else { bo.x = 0.0f; bo.y = 0.0f; bo.z = 0.0f; bo.w = 0.0f; }
        *(float4*)(o_bx + ((size_t)(c * KDET + k)) * 4) = bo;
    }
}

// ---------------- single launch: 144 homogeneous blocks; 0..79 also consume ----------------
__global__ __launch_bounds__(TPB) void nms_pc(const float* __restrict__ scores,
                                              const float* __restrict__ boxes,
                                              uint64_t* __restrict__ list,
                                              int* __restrict__ subcnt,
                                              uint32_t* __restrict__ flags,
                                              float* __restrict__ out) {
    const int blk = blockIdx.x, tid = threadIdx.x;
    const int lane = tid & 63, wid = tid >> 6;
    __shared__ ChunkShared S;
    __shared__ int hist[NBINS];
    __shared__ int lcnt[NCLS];
    __shared__ int s_wtot[TPB / 64];
    __shared__ int s_ov, s_cnt, s_lo;

    // ===== PROBE: produce replicated PRODUCE_REPS times (idempotent), then single flag =====
    for (int rep = 0; rep < PRODUCE_REPS; rep++) {
        for (int cc = tid; cc < NCLS; cc += TPB) lcnt[cc] = 0;
        __syncthreads();
        {
            const float4* sc4 = (const float4*)scores;
            const int stride = GRID * TPB;               // 147456 (~6.7 quads/thread)
            int q = blk * TPB + tid;
            for (; q + 3 * stride < QTOT; q += 4 * stride) {
                float4 v0 = sc4[q], v1 = sc4[q + stride];
                float4 v2 = sc4[q + 2 * stride], v3 = sc4[q + 3 * stride];
                collect_quad(q, v0, lcnt, list, blk);
                collect_quad(q + stride, v1, lcnt, list, blk);
                collect_quad(q + 2 * stride, v2, lcnt, list, blk);
                collect_quad(q + 3 * stride, v3, lcnt, list, blk);
            }
            for (; q < QTOT; q += stride) collect_quad(q, sc4[q], lcnt, list, blk);
        }
        __syncthreads();
        for (int cc = tid; cc < NCLS; cc += TPB) st_agent_u32(&subcnt[cc * NBLK + blk], lcnt[cc]);
        __syncthreads();  // final rep: vmcnt(0) drain => stores globally visible before flag
    }
    if (tid == 0)
        __hip_atomic_store(&flags[blk], FLAG_MAGIC | (uint32_t)blk,
                           __ATOMIC_RELEASE, __HIP_MEMORY_SCOPE_AGENT);
    if (blk >= NCONS) return;                            // blocks 80..143: produce-only

    // ---- consume: block c == class c ----
    const int c = blk;
    if (tid == 0) s_ov = 0;
    int raw = 0;
    uint64_t pre0 = 0, pre1 = 0, pre2 = 0, pre3 = 0;
    {
        // latched RELAXED polling; prefetch own producer's subcnt + first 4 list entries
        bool ready = (tid >= NBLK);
        const uint32_t exp0 = FLAG_MAGIC | (uint32_t)tid;
        const uint64_t* src = list + ((size_t)c * NBLK + tid) * SUBCAP;
        while (true) {
            if (!ready && ld_agent_flag(&flags[tid]) == exp0) {
                ready = true;
                raw = ld_agent_i32(&subcnt[c * NBLK + tid]);
                const int vp = min(raw, SUBCAP);
                if (vp > 0) pre0 = ld_agent_u64(&src[0]);
                if (vp > 1) pre1 = ld_agent_u64(&src[1]);
                if (vp > 2) pre2 = ld_agent_u64(&src[2]);
                if (vp > 3) pre3 = ld_agent_u64(&src[3]);
            }
            if (__syncthreads_and((int)ready)) break;
            __builtin_amdgcn_s_sleep(2);
        }
    }
    int kc = 0;
    bool fast = false;
    {
        if (raw > SUBCAP) atomicOr(&s_ov, 1);
        const int v = (tid < NBLK) ? min(raw, SUBCAP) : 0;
        int incl = v;                                    // wave-inclusive scan via shuffles
        for (int d = 1; d < 64; d <<= 1) {
            int o = __shfl_up(incl, d, 64);
            if (lane >= d) incl += o;
        }
        if (lane == 63) s_wtot[wid] = incl;
        __syncthreads();
        int woff = 0;
        for (int w = 0; w < wid; w++) woff += s_wtot[w];
        const int off = woff + incl - v;
        int M0 = 0;
        for (int w = 0; w < TPB / 64; w++) M0 += s_wtot[w];
        fast = (s_ov == 0) && (M0 <= CAP);
        if (fast && v > 0) {
            S.keys[off] = pre0;                          // prefetched entries from registers
            if (v > 1) S.keys[off + 1] = pre1;
            if (v > 2) S.keys[off + 2] = pre2;
            if (v > 3) S.keys[off + 3] = pre3;
            const uint64_t* src = list + ((size_t)c * NBLK + tid) * SUBCAP;
            for (int k = 4; k < v; k++) S.keys[off + k] = ld_agent_u64(&src[k]);  // rare tail
        }
        __syncthreads();
        if (fast) kc = process_chunk(S, tid, M0, 0, boxes);
    }
    if (kc < KDET) kc = slow_path(S, hist, &s_cnt, &s_lo, c, kc, fast, tid, scores, boxes);
    __syncthreads();
    write_outputs(S, c, kc, tid, out);
}

// ---------------- fallback: exact slow-only kernel (no ws, normal launch) ----------------
__global__ __launch_bounds__(TPB) void nms_slow(const float* __restrict__ scores,
                                                const float* __restrict__ boxes,
                                                float* __restrict__ out) {
    const int c = blockIdx.x, tid = threadIdx.x;
    __shared__ ChunkShared S;
    __shared__ int hist[NBINS];
    __shared__ int s_cnt, s_lo;
    int kc = slow_path(S, hist, &s_cnt, &s_lo, c, 0, false, tid, scores, boxes);
    __syncthreads();
    write_outputs(S, c, kc, tid, out);
}

extern "C" void kernel_launch(void* const* d_in, const int* in_sizes, int n_in,
                              void* d_out, int out_size, void* d_ws, size_t ws_size,
                              hipStream_t stream) {
    const float* scores = (const float*)d_in[0];   // [N, C] f32
    const float* boxes  = (const float*)d_in[1];   // [N, 4] f32
    float* out = (float*)d_out;                    // 56000 f32: scores|classes|boxes|valids

    if (ws_size >= WS_NEED) {
        uint64_t* list   = (uint64_t*)d_ws;
        int*      subcnt = (int*)((char*)d_ws + SUBCNT_OFF);
        uint32_t* flags  = (uint32_t*)((char*)d_ws + FLAGS_OFF);
        nms_pc<<<GRID, TPB, 0, stream>>>(scores, boxes, list, subcnt, flags, out);
        return;
    }
    // exact (slower) fallback: no workspace
    nms_slow<<<NCLS, TPB, 0, stream>>>(scores, boxes, out);
}

// Round 11
// 82.517 us; speedup vs baseline: 1.1658x; 1.1658x over previous
//
#include <hip/hip_runtime.h>
#include <math.h>
#include <stdint.h>

#define N_ANCH 49104
#define NCLS 80
#define KDET 100
#define CAP 256              // chunk size (candidates per NMS chunk)
#define TPB 1024             // 16 waves/block
#define NBINS 1024
#define NBLK 144             // total blocks; ALL produce (1/144 slice each)
#define NCONS 80             // blocks 0..79 also consume (1 class each)
#define GRID NBLK            // 144 blocks; 16 waves + ~23KB LDS -> 2 blocks/CU cap >= 144
#define SUBCAP 16            // slots per (class, block) sub-list
#define THETA 0.996579f      // targets ~168 candidates/class; exact fallback if wrong
#define QTOT (N_ANCH * NCLS / 4)   // 982080 float4 quads
#define JMAX 16              // Jacobi round bound (serial fallback if exceeded)
#define FLAG_MAGIC 0x5AC10000u     // | block id
#define PADKEY(t) ((0xFFFFFFFFull << 16) | (uint64_t)(t))

// ws layout: list [NCLS*NBLK*SUBCAP u64] | subcnt [NCLS*NBLK int] | flags [NBLK u32]
#define LIST_ELEMS ((size_t)NCLS * NBLK * SUBCAP)
#define SUBCNT_OFF (LIST_ELEMS * 8)
#define FLAGS_OFF (SUBCNT_OFF + (size_t)NCLS * NBLK * 4)
#define WS_NEED (FLAGS_OFF + (size_t)NBLK * 4)

// Cross-XCD message passing WITHOUT cache maintenance (relaxed agent-scope atomics;
// producer's __syncthreads drains vmcnt(0) before the flag store).
__device__ __forceinline__ void st_agent_u64(uint64_t* p, uint64_t v) {
    __hip_atomic_store(p, v, __ATOMIC_RELAXED, __HIP_MEMORY_SCOPE_AGENT);
}
__device__ __forceinline__ void st_agent_u32(int* p, int v) {
    __hip_atomic_store(p, v, __ATOMIC_RELAXED, __HIP_MEMORY_SCOPE_AGENT);
}
__device__ __forceinline__ uint64_t ld_agent_u64(const uint64_t* p) {
    return __hip_atomic_load(p, __ATOMIC_RELAXED, __HIP_MEMORY_SCOPE_AGENT);
}
__device__ __forceinline__ int ld_agent_i32(const int* p) {
    return __hip_atomic_load(p, __ATOMIC_RELAXED, __HIP_MEMORY_SCOPE_AGENT);
}
__device__ __forceinline__ uint32_t ld_agent_flag(const uint32_t* p) {
    return __hip_atomic_load(p, __ATOMIC_RELAXED, __HIP_MEMORY_SCOPE_AGENT);
}

// ---------------- produce helper ----------------
__device__ __forceinline__ void collect_quad(int q, float4 v, int* lcnt,
                                             uint64_t* __restrict__ list, int blk) {
    const int n = q / 20;            // anchor: 4q/80
    const int c0 = 4 * (q % 20);     // first class of quad
    float ss[4] = {v.x, v.y, v.z, v.w};
#pragma unroll
    for (int u = 0; u < 4; u++) {
        float s = ss[u];
        if (s > THETA) {
            int c = c0 + u;
            int p = atomicAdd(&lcnt[c], 1);              // LDS atomic only
            if (p < SUBCAP) {
                uint32_t bits = __float_as_uint(s);      // s>0: bit order == value order
                st_agent_u64(&list[((size_t)c * NBLK + blk) * SUBCAP + p],
                             ((uint64_t)(~bits) << 16) | (uint64_t)n);   // score desc, anchor asc
            }
        }
    }
}

// ---------------- shared state for the per-class core ----------------
// ra[] eliminated: areas recomputed from box coords at each use ((z-x)*(w-y) on identical
// float4 values -> bit-identical IoU everywhere).
struct ChunkShared {
    uint64_t keys[CAP];                // real keys at [0,M)
    float4   rbox[CAP];                // boxes in sorted (rank) order
    float    rs[CAP];
    uint64_t smat[CAP * (CAP / 64)];   // ST: column i = "who suppresses i" (j < i)
    uint64_t lwbuf[CAP / 64];          // alive ballot words
    uint64_t s_kw[CAP / 64];           // kept ballot words (Jacobi / result)
    int      s_cw[4];                  // per-victim-word change flags
    float4   kbox[KDET];
    float    kar[KDET], ksc[KDET];
};

__device__ __forceinline__ float box_area(float4 b) {
    return (b.z - b.x) * (b.w - b.y);
}

// rank-sort (M-bounded, b128-paired) -> scatter -> filter-vs-kept -> ST ballots (16-wave
// split, victim prefetch) -> Jacobi fixpoint -> parallel extract. Exact; fallback retained.
// PRE: S.keys[0..M) populated with real keys (unique), barrier done.
__device__ __forceinline__ int process_chunk(ChunkShared& S, int tid, int M, int kc0,
                                             const float* __restrict__ boxes) {
    if (M <= 0) return kc0;                       // uniform across block
    const int lane = tid & 63, wid = tid >> 6;    // wid 0..15
    if (tid < M) {
        const uint64_t key = S.keys[tid];
        const int n = (int)(key & 0xFFFFull);     // real keys only: n < N_ANCH
        const float4 mybox = *(const float4*)(boxes + (size_t)n * 4);
        int rank = 0;
        const int Me = M & ~1;
#pragma unroll 4
        for (int j = 0; j < Me; j += 2) {
            const ulonglong2 kk = *(const ulonglong2*)&S.keys[j];
            rank += (kk.x < key) ? 1 : 0;
            rank += (kk.y < key) ? 1 : 0;
        }
        if (Me < M) rank += (S.keys[Me] < key) ? 1 : 0;
        S.rbox[rank] = mybox;
        S.rs[rank] = __uint_as_float(~((uint32_t)(key >> 16)));
    }
    __syncthreads();
    // ---- filter vs previously-kept boxes (exact chunk continuation) ----
    bool alive = (tid < M);
    if (alive && kc0 > 0) {
        float4 b = S.rbox[tid];
        float arb = box_area(b);
        for (int k2 = 0; k2 < kc0; k2++) {
            float4 kb = S.kbox[k2];
            float ix1 = fmaxf(kb.x, b.x), iy1 = fmaxf(kb.y, b.y);
            float ix2 = fminf(kb.z, b.z), iy2 = fminf(kb.w, b.w);
            float inter = fmaxf(ix2 - ix1, 0.0f) * fmaxf(iy2 - iy1, 0.0f);
            float iou = inter / (S.kar[k2] + arb - inter + 1e-8f);
            if (iou > 0.5f) { alive = false; break; }
        }
    }
    {
        uint64_t bal = __ballot(alive);
        if (lane == 0 && wid < 4) S.lwbuf[wid] = bal;
    }
    // no barrier: lwbuf only read in the serial fallback (behind Jacobi barriers);
    // ST reads rbox (post-scatter barrier) and writes smat (read after post-ST barrier).
    // ---- ST bitmatrix: 10 (vw,ws) pairs over 16 waves; next-victim prefetch ----
    {
        int p, istart, istep;
        if (wid < 12) { p = wid >> 1; istart = wid & 1; istep = 2; }
        else          { p = wid - 6;  istart = 0;       istep = 1; }
        const int vw = (int)((0x3333222110ull >> (4 * p)) & 0xF);   // victim word
        const int ws = (int)((0x3210210100ull >> (4 * p)) & 0xF);   // suppressor word
        const int i0 = vw << 6;
        if (i0 < M) {
            const int i1 = min(M, i0 + 64);
            const int jj = (ws << 6) + lane;
            float4 bj = S.rbox[jj];                // jj>=M only when ws==vw: masked by jj<i
            float arj = box_area(bj);
            int ifirst = i0 + istart;
            float4 bi = S.rbox[ifirst < i1 ? ifirst : i0];   // victim prefetch (broadcast)
            for (int i = ifirst; i < i1; i += istep) {
                float4 bin = bi;
                if (i + istep < i1) bin = S.rbox[i + istep];
                bool bit = false;
                if (jj < i) {
                    float ari = box_area(bi);
                    float ix1 = fmaxf(bj.x, bi.x), iy1 = fmaxf(bj.y, bi.y);
                    float ix2 = fminf(bj.z, bi.z), iy2 = fminf(bj.w, bi.w);
                    float inter = fmaxf(ix2 - ix1, 0.0f) * fmaxf(iy2 - iy1, 0.0f);
                    float iou = inter / (arj + ari - inter + 1e-8f);   // fp-identical to ref
                    bit = iou > 0.5f;
                }
                uint64_t bb = __ballot(bit);
                if (lane == 0) S.smat[((size_t)i << 2) + ws] = bb;
                bi = bin;
            }
        }
    }
    __syncthreads();
    // ---- my ST column into registers ----
    uint64_t st0 = 0, st1 = 0, st2 = 0, st3 = 0;
    if (tid < M) {
        st0 = S.smat[((size_t)tid << 2) + 0];
        if (wid >= 1) st1 = S.smat[((size_t)tid << 2) + 1];
        if (wid >= 2) st2 = S.smat[((size_t)tid << 2) + 2];
        if (wid >= 3) st3 = S.smat[((size_t)tid << 2) + 3];
    }
    // ---- Jacobi to fixpoint ----
    bool kept = alive;
    bool converged = false;
    for (int it = 0; it < JMAX; it++) {
        uint64_t kb = __ballot(kept);
        if (lane == 0 && wid < 4) S.s_kw[wid] = kb;
        __syncthreads();
        const uint64_t k0 = S.s_kw[0], k1 = S.s_kw[1], k2 = S.s_kw[2], k3 = S.s_kw[3];
        const bool sup = ((k0 & st0) | (k1 & st1) | (k2 & st2) | (k3 & st3)) != 0ull;
        const bool nk = alive && !sup;
        uint64_t cb = __ballot(nk != kept);
        if (lane == 0 && wid < 4) S.s_cw[wid] = (cb != 0ull) ? 1 : 0;
        kept = nk;
        __syncthreads();
        if ((S.s_cw[0] | S.s_cw[1] | S.s_cw[2] | S.s_cw[3]) == 0) { converged = true; break; }
    }
    if (!converged) {                              // exact serial fallback
        if (tid == 0) {
            uint64_t lv[4] = {S.lwbuf[0], S.lwbuf[1], S.lwbuf[2], S.lwbuf[3]};
            uint64_t kw[4] = {0, 0, 0, 0};
            for (int i = 0; i < M; i++) {
                const int w = i >> 6, b = i & 63;
                if (!((lv[w] >> b) & 1ull)) continue;
                const uint64_t* row = &S.smat[(size_t)i << 2];
                uint64_t sup = kw[0] & row[0];
                if (w >= 1) sup |= kw[1] & row[1];
                if (w >= 2) sup |= kw[2] & row[2];
                if (w >= 3) sup |= kw[3] & row[3];
                if (!sup) kw[w] |= 1ull << b;
            }
            S.s_kw[0] = kw[0]; S.s_kw[1] = kw[1]; S.s_kw[2] = kw[2]; S.s_kw[3] = kw[3];
        }
        __syncthreads();
    }
    // ---- parallel extraction in greedy (index) order ----
    const uint64_t k0 = S.s_kw[0], k1 = S.s_kw[1], k2 = S.s_kw[2], k3 = S.s_kw[3];
    const int total = __popcll(k0) + __popcll(k1) + __popcll(k2) + __popcll(k3);
    const uint64_t mykw = (wid == 0) ? k0 : (wid == 1) ? k1 : (wid == 2) ? k2 : k3;
    if (tid < M && ((mykw >> lane) & 1ull)) {
        int rk = __popcll(mykw & ((1ull << lane) - 1ull));
        if (wid > 0) rk += __popcll(k0);
        if (wid > 1) rk += __popcll(k1);
        if (wid > 2) rk += __popcll(k2);
        const int r = kc0 + rk;
        if (r < KDET) {
            float4 rb = S.rbox[tid];
            S.kbox[r] = rb;
            S.kar[r] = box_area(rb);
            S.ksc[r] = S.rs[tid];
        }
    }
    __syncthreads();
    return min(kc0 + total, KDET);
}

// ---------------- exact slow path ----------------
__device__ __forceinline__ int slow_path(ChunkShared& S, int* hist, int* s_cnt, int* s_lo,
                                         int c, int kc, bool fast, int tid,
                                         const float* __restrict__ scores,
                                         const float* __restrict__ boxes) {
    const float hicut = fast ? THETA : 3.0e38f;
    if (!fast) kc = 0;
    for (int b = tid; b < NBINS; b += TPB) hist[b] = 0;
    __syncthreads();
    for (int n = tid; n < N_ANCH; n += TPB) {
        float s = scores[(size_t)n * NCLS + c];
        if (s > 0.05f && s <= hicut) {
            int b = (int)(s * 1024.0f);
            b = b < 0 ? 0 : (b > NBINS - 1 ? NBINS - 1 : b);
            atomicAdd(&hist[b], 1);
        }
    }
    __syncthreads();
    int hi = NBINS;
    while (hi > 0 && kc < KDET) {
        if (tid == 0) {
            int lo = hi, tot = 0;
            while (lo > 0 && tot + hist[lo - 1] <= CAP) { lo--; tot += hist[lo]; }
            if (lo == hi) lo = hi - 1;
            *s_lo = lo; *s_cnt = 0;
        }
        __syncthreads();
        const int lo = *s_lo;
        for (int n = tid; n < N_ANCH; n += TPB) {
            float s = scores[(size_t)n * NCLS + c];
            if (s > 0.05f && s <= hicut) {
                int b = (int)(s * 1024.0f);
                b = b < 0 ? 0 : (b > NBINS - 1 ? NBINS - 1 : b);
                if (b >= lo && b < hi) {
                    int p = atomicAdd(s_cnt, 1);
                    if (p < CAP) {
                        uint32_t bits = __float_as_uint(s);
                        S.keys[p] = ((uint64_t)(~bits) << 16) | (uint64_t)n;
                    }
                }
            }
        }
        __syncthreads();
        const int M2 = min(*s_cnt, CAP);
        kc = process_chunk(S, tid, M2, kc, boxes);
        hi = lo;
    }
    return kc;
}

// ---------------- output epilogue ----------------
__device__ __forceinline__ void write_outputs(ChunkShared& S, int c, int kc, int tid,
                                              float* __restrict__ out) {
    float* o_sc = out;
    float* o_cl = out + NCLS * KDET;
    float* o_bx = out + 2 * NCLS * KDET;
    float* o_va = out + 6 * NCLS * KDET;
    for (int k = tid; k < KDET; k += TPB) {
        bool valid = k < kc;
        o_sc[c * KDET + k] = valid ? S.ksc[k] : 0.0f;
        o_cl[c * KDET + k] = (float)c;
        o_va[c * KDET + k] = valid ? 1.0f : 0.0f;
        float4 bo;
        if (valid) bo = S.kbox[k];
        else { bo.x = 0.0f; bo.y = 0.0f; bo.z = 0.0f; bo.w = 0.0f; }
        *(float4*)(o_bx + ((size_t)(c * KDET + k)) * 4) = bo;
    }
}

// ---------------- single launch: 144 homogeneous blocks; 0..79 also consume ----------------
// Every block produces its 1/144 slice, then blocks 0..79 poll all 144 flags and run their
// class. Consumers prefetch their own producer's subcnt + first 4 list entries into regs
// the moment that producer's flag lands. Co-residency: 144 blocks <= 2/CU * 256 CUs =>
// spin-wait cannot deadlock.
__global__ __launch_bounds__(TPB) void nms_pc(const float* __restrict__ scores,
                                              const float* __restrict__ boxes,
                                              uint64_t* __restrict__ list,
                                              int* __restrict__ subcnt,
                                              uint32_t* __restrict__ flags,
                                              float* __restrict__ out) {
    const int blk = blockIdx.x, tid = threadIdx.x;
    const int lane = tid & 63, wid = tid >> 6;
    __shared__ ChunkShared S;
    __shared__ int hist[NBINS];
    __shared__ int lcnt[NCLS];
    __shared__ int s_wtot[TPB / 64];
    __shared__ int s_ov, s_cnt, s_lo;

    // ---- produce: every block collects its slice (coalesced float4, 4 loads in flight) ----
    for (int cc = tid; cc < NCLS; cc += TPB) lcnt[cc] = 0;
    __syncthreads();
    {
        const float4* sc4 = (const float4*)scores;
        const int stride = GRID * TPB;                   // 147456 (~6.7 quads/thread)
        int q = blk * TPB + tid;
        for (; q + 3 * stride < QTOT; q += 4 * stride) {
            float4 v0 = sc4[q], v1 = sc4[q + stride];
            float4 v2 = sc4[q + 2 * stride], v3 = sc4[q + 3 * stride];
            collect_quad(q, v0, lcnt, list, blk);
            collect_quad(q + stride, v1, lcnt, list, blk);
            collect_quad(q + 2 * stride, v2, lcnt, list, blk);
            collect_quad(q + 3 * stride, v3, lcnt, list, blk);
        }
        for (; q < QTOT; q += stride) collect_quad(q, sc4[q], lcnt, list, blk);
    }
    __syncthreads();
    for (int cc = tid; cc < NCLS; cc += TPB) st_agent_u32(&subcnt[cc * NBLK + blk], lcnt[cc]);
    __syncthreads();  // s_waitcnt vmcnt(0): all uncached list/subcnt stores globally visible
    if (tid == 0)
        __hip_atomic_store(&flags[blk], FLAG_MAGIC | (uint32_t)blk,
                           __ATOMIC_RELEASE, __HIP_MEMORY_SCOPE_AGENT);
    if (blk >= NCONS) return;                            // blocks 80..143: produce-only

    // ---- consume: block c == class c ----
    const int c = blk;
    if (tid == 0) s_ov = 0;
    int raw = 0;
    uint64_t pre0 = 0, pre1 = 0, pre2 = 0, pre3 = 0;
    {
        // latched RELAXED polling; prefetch own producer's subcnt + first 4 list entries
        // the moment its flag lands (producer's release ordered data before flag).
        bool ready = (tid >= NBLK);
        const uint32_t exp0 = FLAG_MAGIC | (uint32_t)tid;
        const uint64_t* src = list + ((size_t)c * NBLK + tid) * SUBCAP;
        while (true) {
            if (!ready && ld_agent_flag(&flags[tid]) == exp0) {
                ready = true;
                raw = ld_agent_i32(&subcnt[c * NBLK + tid]);
                const int vp = min(raw, SUBCAP);
                if (vp > 0) pre0 = ld_agent_u64(&src[0]);
                if (vp > 1) pre1 = ld_agent_u64(&src[1]);
                if (vp > 2) pre2 = ld_agent_u64(&src[2]);
                if (vp > 3) pre3 = ld_agent_u64(&src[3]);
            }
            if (__syncthreads_and((int)ready)) break;
            __builtin_amdgcn_s_sleep(2);
        }
    }
    int kc = 0;
    bool fast = false;
    {
        if (raw > SUBCAP) atomicOr(&s_ov, 1);
        const int v = (tid < NBLK) ? min(raw, SUBCAP) : 0;
        int incl = v;                                    // wave-inclusive scan via shuffles
        for (int d = 1; d < 64; d <<= 1) {
            int o = __shfl_up(incl, d, 64);
            if (lane >= d) incl += o;
        }
        if (lane == 63) s_wtot[wid] = incl;
        __syncthreads();
        int woff = 0;
        for (int w = 0; w < wid; w++) woff += s_wtot[w];
        const int off = woff + incl - v;
        int M0 = 0;
        for (int w = 0; w < TPB / 64; w++) M0 += s_wtot[w];
        fast = (s_ov == 0) && (M0 <= CAP);
        if (fast && v > 0) {
            S.keys[off] = pre0;                          // prefetched entries from registers
            if (v > 1) S.keys[off + 1] = pre1;
            if (v > 2) S.keys[off + 2] = pre2;
            if (v > 3) S.keys[off + 3] = pre3;
            const uint64_t* src = list + ((size_t)c * NBLK + tid) * SUBCAP;
            for (int k = 4; k < v; k++) S.keys[off + k] = ld_agent_u64(&src[k]);  // rare tail
        }
        __syncthreads();
        if (fast) kc = process_chunk(S, tid, M0, 0, boxes);
    }
    if (kc < KDET) kc = slow_path(S, hist, &s_cnt, &s_lo, c, kc, fast, tid, scores, boxes);
    __syncthreads();
    write_outputs(S, c, kc, tid, out);
}

// ---------------- fallback: exact slow-only kernel (no ws, normal launch) ----------------
__global__ __launch_bounds__(TPB) void nms_slow(const float* __restrict__ scores,
                                                const float* __restrict__ boxes,
                                                float* __restrict__ out) {
    const int c = blockIdx.x, tid = threadIdx.x;
    __shared__ ChunkShared S;
    __shared__ int hist[NBINS];
    __shared__ int s_cnt, s_lo;
    int kc = slow_path(S, hist, &s_cnt, &s_lo, c, 0, false, tid, scores, boxes);
    __syncthreads();
    write_outputs(S, c, kc, tid, out);
}

extern "C" void kernel_launch(void* const* d_in, const int* in_sizes, int n_in,
                              void* d_out, int out_size, void* d_ws, size_t ws_size,
                              hipStream_t stream) {
    const float* scores = (const float*)d_in[0];   // [N, C] f32
    const float* boxes  = (const float*)d_in[1];   // [N, 4] f32
    float* out = (float*)d_out;                    // 56000 f32: scores|classes|boxes|valids

    if (ws_size >= WS_NEED) {
        uint64_t* list   = (uint64_t*)d_ws;
        int*      subcnt = (int*)((char*)d_ws + SUBCNT_OFF);
        uint32_t* flags  = (uint32_t*)((char*)d_ws + FLAGS_OFF);
        nms_pc<<<GRID, TPB, 0, stream>>>(scores, boxes, list, subcnt, flags, out);
        return;
    }
    // exact (slower) fallback: no workspace
    nms_slow<<<NCLS, TPB, 0, stream>>>(scores, boxes, out);
}